// Round 6
// baseline (176.075 us; speedup 1.0000x reference)
//
#include <hip/hip_runtime.h>
#include <math.h>

#define B_ 8
#define N_ 256
#define F_ 512
#define H_ 256

typedef __attribute__((ext_vector_type(8))) short short8;
typedef __attribute__((ext_vector_type(4))) float floatx4;
typedef _Float16 h2 __attribute__((ext_vector_type(2)));

__device__ __forceinline__ unsigned int f2bf_bits(float f) {
    unsigned int u = __float_as_uint(f);
    return (u + 0x7fffu + ((u >> 16) & 1u)) >> 16;   // RNE
}
__device__ __forceinline__ unsigned int pack2bf(float a, float b) {
    return f2bf_bits(a) | (f2bf_bits(b) << 16);
}
__device__ __forceinline__ h2 as_h2(unsigned int u) {
    union { unsigned int u; h2 h; } x; x.u = u; return x.h;
}
__device__ __forceinline__ h2 relu2(h2 t) {
    h2 z; z.x = (_Float16)0; z.y = (_Float16)0;
#if __has_builtin(__builtin_elementwise_max)
    return __builtin_elementwise_max(t, z);
#else
    t.x = t.x > z.x ? t.x : z.x;
    t.y = t.y > z.y ? t.y : z.y;
    return t;
#endif
}
__device__ __forceinline__ float fast_sigmoid(float x) {
    return 1.f / (1.f + __expf(-x));     // v_exp_f32 path; err ~1e-6 << 0.0039 tol
}

// ---------------------------------------------------------------------------
// bf16 MFMA GEMM with generalized operand staging (prep dispatch eliminated;
// transposes/conversions happen in-staging at the consumer):
//   mode 0: bf16 rows  [idx][k], ld elems        (prepped / intermediate)
//   mode 1: fp32 rows  [idx][k], pack->bf16      (activations, ftW2 rows)
//   mode 2: fp32 cols  src[k*ld + idx] gather    (in-staging transpose of
//            row-major weight W[k][n] -> per-thread 8 strided dwords; per wave
//            4 x 64B segments per load, L2-served, reused across blocks)
// 64x64 tile, BK=32, 256 thr (4 waves). Single-barrier double-buffered LDS,
// register prefetch issued before the barrier (loads span barrier + MFMA).
// outMode: 0=f32, 1=bf16, 2=f16.
// NOTE (R4 lesson): phases stay separate dispatches — a device-scope software
// barrier costs ~40us on gfx950 (XCD L2 flush), vs ~2us dispatch gap.
// ---------------------------------------------------------------------------
struct GJob {
    const void* A0; const void* A1; int aSplitBlk; int aMode; int ldA;
    const void* B0; const void* B1; int bMode; int ldB;
    const float* bias0; const float* bias1;
    int wRowSplitBlk; int wColSplitBlk;
    void* out; int outMode; int ldOut; int K; int relu;
};

struct SpecP {   // special blocks folded into the first GEMM dispatch
    const float* slW1a; const float* slW1b; const float* ftb2; const float* slb1;
    float* bA; float* bB; float* accum;
};

struct Pref { uint4 u; float4 f0, f1; float fs[8]; };

__device__ __forceinline__ void op_load(Pref& P, int mode, const void* base,
                                        int ld, int row, int k)
{
    if (mode == 0) {
        P.u = *(const uint4*)((const unsigned short*)base + (size_t)row * ld + k);
    } else if (mode == 1) {
        const float* s = (const float*)base + (size_t)row * ld + k;
        P.f0 = *(const float4*)s;
        P.f1 = *(const float4*)(s + 4);
    } else {
        const float* s = (const float*)base + (size_t)k * ld + row;
#pragma unroll
        for (int jj = 0; jj < 8; ++jj) P.fs[jj] = s[(size_t)jj * ld];
    }
}
__device__ __forceinline__ uint4 to_bf(const Pref& P, int mode)
{
    if (mode == 0) return P.u;
    if (mode == 1) return make_uint4(pack2bf(P.f0.x, P.f0.y), pack2bf(P.f0.z, P.f0.w),
                                     pack2bf(P.f1.x, P.f1.y), pack2bf(P.f1.z, P.f1.w));
    return make_uint4(pack2bf(P.fs[0], P.fs[1]), pack2bf(P.fs[2], P.fs[3]),
                      pack2bf(P.fs[4], P.fs[5]), pack2bf(P.fs[6], P.fs[7]));
}

// bias blocks: bA = ftb2 @ slW1a ; bB = ftb2 @ slW1b + slb1 ; accum zero.
__device__ void special_block(const SpecP& sp, int bx)
{
    const int tid = threadIdx.x;
    if (bx == 2) { if (tid < 4) sp.accum[tid] = 0.f; return; }
    if (bx > 2) return;
    const float* W = bx ? sp.slW1b : sp.slW1a;
    const int n = tid;
    float s[16];
#pragma unroll
    for (int u = 0; u < 16; ++u) s[u] = 0.f;
    for (int k0 = 0; k0 < 256; k0 += 16) {     // 16-way ILP: 16 loads in flight
#pragma unroll
        for (int u = 0; u < 16; ++u)
            s[u] = fmaf(sp.ftb2[k0 + u], W[(size_t)(k0 + u) * 256 + n], s[u]);
    }
    float t = 0.f;
#pragma unroll
    for (int u = 0; u < 16; ++u) t += s[u];
    if (bx) sp.bB[n] = t + sp.slb1[n];
    else    sp.bA[n] = t;
}

// by < j1By -> job1 (scheduled first); by == spBy -> special; else job0.
__global__ __launch_bounds__(256) void gemm_mfma(GJob j0, GJob j1, int j1By,
                                                 int spBy, SpecP sp)
{
    __shared__ unsigned short As[2][64][40];   // [buf][row][k], pad 32->40
    __shared__ unsigned short Bs[2][64][40];   // [buf][col][k]

    const int byG = blockIdx.x == blockIdx.x ? (int)blockIdx.y : 0;
    if (byG == spBy) { special_block(sp, blockIdx.x); return; }

    const bool isJ1 = byG < j1By;
    const GJob j = isJ1 ? j1 : j0;
    const int by = isJ1 ? byG : byG - j1By - (spBy >= 0 ? 1 : 0);
    const int bx = blockIdx.x;
    const int tid = threadIdx.x;
    const int K = j.K;

    const void* Abase; int arow0;
    if (by < j.aSplitBlk) { Abase = j.A0; arow0 = by * 64; }
    else                  { Abase = j.A1; arow0 = (by - j.aSplitBlk) * 64; }

    int wcolBlk = bx;
    bool second;
    if (j.wColSplitBlk > 0) {
        second = (bx >= j.wColSplitBlk);
        if (second) wcolBlk = bx - j.wColSplitBlk;
    } else {
        second = (by >= j.wRowSplitBlk);
    }
    const void* Bbase     = second ? j.B1 : j.B0;
    const float* bias     = second ? j.bias1 : j.bias0;
    const int wcol = wcolBlk * 64;

    const int r    = tid >> 2;          // 0..63 staging row (A) / col (B)
    const int kq   = (tid & 3) * 8;     // k offset within BK
    const int lane = tid & 63;
    const int wv   = tid >> 6;          // wave id 0..3
    const int col  = lane & 15;
    const int quad = lane >> 4;

    floatx4 acc[4] = {};

    Pref PA, PB;
    op_load(PA, j.aMode, Abase, j.ldA, arow0 + r, kq);
    op_load(PB, j.bMode, Bbase, j.ldB, wcol + r, kq);

    int p = 0;
    for (int k0 = 0; k0 < K; k0 += 32) {
        uint4 aw = to_bf(PA, j.aMode);
        uint4 bw = to_bf(PB, j.bMode);

        *(uint4*)&As[p][r][kq] = aw;
        *(uint4*)&Bs[p][r][kq] = bw;

        if (k0 + 32 < K) {               // prefetch next step; in flight across barrier
            op_load(PA, j.aMode, Abase, j.ldA, arow0 + r, k0 + 32 + kq);
            op_load(PB, j.bMode, Bbase, j.ldB, wcol + r, k0 + 32 + kq);
        }

        __syncthreads();

        short8 bfrag = *(const short8*)&Bs[p][wv * 16 + col][quad * 8];
#pragma unroll
        for (int tm = 0; tm < 4; ++tm) {
            short8 afrag = *(const short8*)&As[p][tm * 16 + col][quad * 8];
            acc[tm] = __builtin_amdgcn_mfma_f32_16x16x32_bf16(afrag, bfrag, acc[tm], 0, 0, 0);
        }
        p ^= 1;
    }

    // D layout: col = lane&15, row = quad*4 + reg  [m89]
    const int ocol = bx * 64 + wv * 16 + col;
    const int bcol = wcol + wv * 16 + col;
    const float bv = bias ? bias[bcol] : 0.f;
#pragma unroll
    for (int tm = 0; tm < 4; ++tm) {
#pragma unroll
        for (int rr = 0; rr < 4; ++rr) {
            float v = acc[tm][rr] + bv;
            if (j.relu) v = fmaxf(v, 0.f);
            const size_t o = (size_t)(by * 64 + tm * 16 + quad * 4 + rr) * j.ldOut + ocol;
            if (j.outMode == 0)      ((float*)j.out)[o] = v;
            else if (j.outMode == 1) ((unsigned short*)j.out)[o] = (unsigned short)f2bf_bits(v);
            else                     ((_Float16*)j.out)[o] = (_Float16)v;
        }
    }
}

// ---------------------------------------------------------------------------
// Pair-score: out[b,i,j] = sigmoid( sum_h relu(a[b,i,h]+c[b,j,h])*W2[h] + b2 )
// a, c are f16 with row strides ldA/ldC. Block tile 64x32 (grid 8x4x8 = 256
// blocks = 1/CU), per-thread 4x2. Swizzle: 16B chunk ch of row r lives at
// ch ^ ((r>>1)&7): a-reads hit 4 distinct slots, c-reads 2-way (free).
// ---------------------------------------------------------------------------
__global__ __launch_bounds__(256) void pair_score(
    const unsigned short* __restrict__ Abase, int ldA,
    const unsigned short* __restrict__ Cbase, int ldC,
    const float* __restrict__ W2, const float* __restrict__ b2p,
    float* __restrict__ out)
{
    __shared__ unsigned short aS[64][256];   // 32 KB
    __shared__ unsigned short cS[32][256];   // 16 KB

    const int tid = threadIdx.x;
    const int b   = blockIdx.z;
    const int i0b = blockIdx.y * 64;
    const int j0b = blockIdx.x * 32;

    {
        const int rr = tid >> 3;         // 0..31
        const int c8 = tid & 7;
#pragma unroll
        for (int rep = 0; rep < 8; ++rep) {
            const int li = rr + 32 * (rep & 1);
            const int ch = c8 + 8 * (rep >> 1);
            uint4 v = *(const uint4*)(Abase + ((size_t)b * N_ + i0b + li) * ldA + ch * 8);
            *(uint4*)&aS[li][(ch ^ ((li >> 1) & 7)) * 8] = v;
        }
#pragma unroll
        for (int rep = 0; rep < 4; ++rep) {
            const int ch = c8 + 8 * rep;
            uint4 v = *(const uint4*)(Cbase + ((size_t)b * N_ + j0b + rr) * ldC + ch * 8);
            *(uint4*)&cS[rr][(ch ^ ((rr >> 1) & 7)) * 8] = v;
        }
    }
    __syncthreads();

    const int ti = tid >> 4, tj = tid & 15;
    const int ia = ti * 4, jc = tj * 2;
    const int k01 = (2 * ti) & 7;        // key for rows ia, ia+1
    const int k23 = (2 * ti + 1) & 7;    // key for rows ia+2, ia+3
    const int kc  = tj & 7;              // key for rows jc, jc+1

    float s[4][2] = {};

#pragma unroll 4
    for (int ch = 0; ch < 32; ++ch) {
        const uint4 a0 = *(const uint4*)&aS[ia    ][(ch ^ k01) * 8];
        const uint4 a1 = *(const uint4*)&aS[ia + 1][(ch ^ k01) * 8];
        const uint4 a2 = *(const uint4*)&aS[ia + 2][(ch ^ k23) * 8];
        const uint4 a3 = *(const uint4*)&aS[ia + 3][(ch ^ k23) * 8];
        const uint4 c0 = *(const uint4*)&cS[jc    ][(ch ^ kc) * 8];
        const uint4 c1 = *(const uint4*)&cS[jc + 1][(ch ^ kc) * 8];
        const float* w = &W2[ch * 8];    // wave-uniform -> s_load
#pragma unroll
        for (int u = 0; u < 4; ++u) {
            const float w0 = w[2 * u], w1 = w[2 * u + 1];
            const h2 hc0 = as_h2(((const unsigned int*)&c0)[u]);
            const h2 hc1 = as_h2(((const unsigned int*)&c1)[u]);
#define ACC2(su, ha, hc) { h2 t_ = relu2((ha) + (hc)); \
    su = fmaf((float)t_.x, w0, su); su = fmaf((float)t_.y, w1, su); }
            {
                const h2 ha = as_h2(((const unsigned int*)&a0)[u]);
                ACC2(s[0][0], ha, hc0); ACC2(s[0][1], ha, hc1);
            }
            {
                const h2 ha = as_h2(((const unsigned int*)&a1)[u]);
                ACC2(s[1][0], ha, hc0); ACC2(s[1][1], ha, hc1);
            }
            {
                const h2 ha = as_h2(((const unsigned int*)&a2)[u]);
                ACC2(s[2][0], ha, hc0); ACC2(s[2][1], ha, hc1);
            }
            {
                const h2 ha = as_h2(((const unsigned int*)&a3)[u]);
                ACC2(s[3][0], ha, hc0); ACC2(s[3][1], ha, hc1);
            }
#undef ACC2
        }
    }

    const float bb = b2p[0];
#pragma unroll
    for (int rr = 0; rr < 4; ++rr) {
        float2 o;
        o.x = fast_sigmoid(s[rr][0] + bb);
        o.y = fast_sigmoid(s[rr][1] + bb);
        *(float2*)&out[((size_t)b * N_ + i0b + ia + rr) * N_ + j0b + jc] = o;
    }
}

// ---------------------------------------------------------------------------
// Invariance with folded finalize: last block (device-scope atomic counter)
// computes the scalar. accum[0]=stab, accum[1]=sd, accum[2]=block counter
// (accum zeroed by the special block in the first GEMM dispatch).
// ---------------------------------------------------------------------------
__global__ __launch_bounds__(256) void invariance_partial(
    const float* __restrict__ causal, float* __restrict__ accum,
    float* __restrict__ out_scalar)
{
    const int idx = blockIdx.x * 256 + threadIdx.x;  // 0..N*N-1
    float x[B_];
#pragma unroll
    for (int b = 0; b < B_; ++b) x[b] = causal[(size_t)b * (N_ * N_) + idx];

    float stab = 0.f, mean = 0.f;
#pragma unroll
    for (int b = 0; b < B_; ++b) {
        stab += fabsf(x[b] - x[(b + B_ - 1) % B_]);
        mean += x[b];
    }
    mean *= (1.f / B_);
    float var = 0.f;
#pragma unroll
    for (int b = 0; b < B_; ++b) {
        float d = x[b] - mean;
        var = fmaf(d, d, var);
    }
    float sd = sqrtf(var * (1.f / (B_ - 1)));

#pragma unroll
    for (int off = 32; off > 0; off >>= 1) {
        stab += __shfl_down(stab, off, 64);
        sd   += __shfl_down(sd, off, 64);
    }

    __shared__ float red[8];
    if ((threadIdx.x & 63) == 0) {
        red[threadIdx.x >> 6]       = stab;
        red[4 + (threadIdx.x >> 6)] = sd;
    }
    __syncthreads();
    if (threadIdx.x == 0) {
        float s = (red[0] + red[1]) + (red[2] + red[3]);
        float d = (red[4] + red[5]) + (red[6] + red[7]);
        atomicAdd(&accum[0], s);
        atomicAdd(&accum[1], d);
        __threadfence();
        unsigned int prev = atomicAdd((unsigned int*)&accum[2], 1u);
        if (prev == 255u) {              // last of 256 blocks
            float st  = atomicAdd(&accum[0], 0.f);   // device-scope read
            float sdt = atomicAdd(&accum[1], 0.f);
            float stability   = st  * (1.f / (float)(B_ * N_ * N_));
            float consistency = sdt * (1.f / (float)(N_ * N_));
            out_scalar[0] = 1.f - (stability + consistency) * 0.5f;
        }
    }
}

// ---------------------------------------------------------------------------
extern "C" void kernel_launch(void* const* d_in, const int* in_sizes, int n_in,
                              void* d_out, int out_size, void* d_ws, size_t ws_size,
                              hipStream_t stream)
{
    const float* img   = (const float*)d_in[0];
    const float* txt   = (const float*)d_in[1];
    const float* ftW1  = (const float*)d_in[2];
    const float* ftb1  = (const float*)d_in[3];
    const float* ftW2  = (const float*)d_in[4];
    const float* ftb2  = (const float*)d_in[5];
    const float* slW1a = (const float*)d_in[6];
    const float* slW1b = (const float*)d_in[7];
    const float* slb1  = (const float*)d_in[8];
    const float* slW2  = (const float*)d_in[9];
    const float* slb2  = (const float*)d_in[10];
    const float* cnW1a = (const float*)d_in[11];
    const float* cnW1b = (const float*)d_in[12];
    const float* cnb1  = (const float*)d_in[13];
    const float* cnW2  = (const float*)d_in[14];
    const float* cnb2  = (const float*)d_in[15];

    float* out       = (float*)d_out;
    float* structure = out;                              // [B,N,N] fp32
    float* causal    = out + (size_t)B_ * N_ * N_;       // [B,N,N] fp32
    float* inv       = out + 2 * (size_t)B_ * N_ * N_;   // scalar

    // workspace layout (ushort units from base):
    //   wcombT  0       .. 131072    [512][256] bf16 (a-half rows 0..255, b-half 256..511)
    //   bA @131072 (f32 x256), bB +256, accum +512  (516 floats)
    //   h1b     135168  .. 1183744   [4096][256] bf16
    //   acb     1183744 .. 2232320   [4096][256] f16 (a;c) / reused [2048][512] f16
    unsigned short* wcombT = (unsigned short*)d_ws;
    float* bA    = (float*)(wcombT + 131072);
    float* bB    = bA + 256;
    float* accum = bA + 512;
    unsigned short* h1b  = wcombT + 135168;
    unsigned short* acb  = wcombT + 1183744;
    unsigned short* ac2b = acb;                          // acb dead after P1

    dim3 blk(256);
    const int BIG = 1 << 20;

    SpecP sp = { slW1a, slW1b, ftb2, slb1, bA, bB, accum };
    SpecP spNull = {};

    // D1: job1 (by 0..7)  = wcombT = (ftW2 @ slW1x)^T  [A: slW1x col-major fp32,
    //                       B: ftW2 row-major fp32], out bf16 [512][256]
    //     by 8            = special blocks (bA, bB, accum zero)
    //     job0 (by 9..72) = G1: [img;txt](4096x512) @ ftW1 + ftb1, relu -> h1b
    //                       [A: fp32 rows, B: ftW1 col-major fp32 (in-staging T)]
    {
        GJob g1  = { img, txt, 32, 1, 512,  ftW1, ftW1, 2, 256,
                     ftb1, ftb1, BIG, 0,  h1b, 1, 256, 512, 1 };
        GJob wcb = { slW1a, slW1b, 4, 2, 256,  ftW2, ftW2, 1, 256,
                     nullptr, nullptr, BIG, 0,  wcombT, 1, 256, 256, 0 };
        gemm_mfma<<<dim3(4, 73), blk, 0, stream>>>(g1, wcb, 8, 8, sp);
    }

    // D2: G2' = h1 @ Wcomb + bias -> acb f16. rows 0..2047 (img): WcombA + bA;
    //     rows 2048.. (txt): WcombB + bB.  (ftW2 folded via associativity)
    {
        GJob g2 = { h1b, h1b, BIG, 0, 256,  wcombT, wcombT + 65536, 0, 256,
                    bA, bB, 32, 0,  acb, 2, 256, 256, 0 };
        gemm_mfma<<<dim3(4, 64), blk, 0, stream>>>(g2, g2, 0, -1, spNull);
    }

    // D3: structure = pair(a, c), f16 inputs
    pair_score<<<dim3(8, 4, 8), blk, 0, stream>>>(
        acb, 256, acb + (size_t)2048 * 256, 256, slW2, slb2, structure);

    // D4: G4 = structure @ [cnW1a | cnW1b(+cnb1)] -> ac2b f16 [2048][512]
    //     [A: fp32 rows, B: cnW1x col-major fp32 (in-staging T)]
    {
        GJob g4 = { structure, structure, BIG, 1, 256,  cnW1a, cnW1b, 2, 256,
                    nullptr, cnb1, BIG, 4,  ac2b, 2, 512, 256, 0 };
        gemm_mfma<<<dim3(8, 32), blk, 0, stream>>>(g4, g4, 0, -1, spNull);
    }

    // D5: causal = pair(a2, c2), f16 inputs
    pair_score<<<dim3(8, 4, 8), blk, 0, stream>>>(
        ac2b, 512, ac2b + 256, 512, cnW2, cnb2, causal);

    // D6: invariance (finalize folded into last block)
    invariance_partial<<<dim3(N_ * N_ / 256), blk, 0, stream>>>(causal, accum, inv);
}

// Round 8
// 162.754 us; speedup vs baseline: 1.0818x; 1.0818x over previous
//
#include <hip/hip_runtime.h>
#include <math.h>

#define B_ 8
#define N_ 256
#define F_ 512
#define H_ 256

typedef __attribute__((ext_vector_type(8))) short short8;
typedef __attribute__((ext_vector_type(4))) float floatx4;
typedef _Float16 h2 __attribute__((ext_vector_type(2)));

__device__ __forceinline__ unsigned int f2bf_bits(float f) {
    unsigned int u = __float_as_uint(f);
    return (u + 0x7fffu + ((u >> 16) & 1u)) >> 16;   // RNE
}
__device__ __forceinline__ unsigned int pack2bf(float a, float b) {
    return f2bf_bits(a) | (f2bf_bits(b) << 16);
}
__device__ __forceinline__ h2 as_h2(unsigned int u) {
    union { unsigned int u; h2 h; } x; x.u = u; return x.h;
}
__device__ __forceinline__ unsigned int h2_bits(h2 h) {
    union { h2 h; unsigned int u; } x; x.h = h; return x.u;
}
__device__ __forceinline__ h2 relu2(h2 t) {
    h2 z; z.x = (_Float16)0; z.y = (_Float16)0;
#if __has_builtin(__builtin_elementwise_max)
    return __builtin_elementwise_max(t, z);
#else
    t.x = t.x > z.x ? t.x : z.x;
    t.y = t.y > z.y ? t.y : z.y;
    return t;
#endif
}
__device__ __forceinline__ float fast_sigmoid(float x) {
    return 1.f / (1.f + __expf(-x));     // v_exp_f32 path; err ~1e-6 << 0.0039 tol
}

// ---------------------------------------------------------------------------
// Weight prep. wt layout (ushort offsets):
//   ftW1^T  @ 0       (256x512)
//   slW1a^T @ 131072  (256x256)
//   slW1b^T @ 196608
//   cnW1a^T @ 262144
//   cnW1b^T @ 327680
//   ftW2row @ 393216  (256x256 bf16, row-major - B operand of Wcomb GEMM)
// Blocks 224/225: combined bias vectors bA = ftb2@slW1a, bB = ftb2@slW1b+slb1,
// plus fp16-pair conversion of slW2/cnW2 (for v_dot2 in pair_score).
// Block 0 additionally zeroes accum[0..3] (replaces a memset dispatch).
// NOTE (R6 lesson): keep this one-time coalesced prep — in-staging transpose
// at the consumers cost +12us (strided loads + register bloat).
// ---------------------------------------------------------------------------
__global__ __launch_bounds__(256) void prep_weights(
    const float* __restrict__ ftW1, const float* __restrict__ ftW2,
    const float* __restrict__ slW1a, const float* __restrict__ slW1b,
    const float* __restrict__ cnW1a, const float* __restrict__ cnW1b,
    const float* __restrict__ ftb2, const float* __restrict__ slb1,
    const float* __restrict__ slW2, const float* __restrict__ cnW2,
    unsigned short* __restrict__ wt, float* __restrict__ bA, float* __restrict__ bB,
    float* __restrict__ accum,
    unsigned int* __restrict__ w2hS, unsigned int* __restrict__ w2hC)
{
    if (blockIdx.x == 0 && threadIdx.x < 4) accum[threadIdx.x] = 0.f;

    if (blockIdx.x >= 224) {              // combined-bias + W2->fp16 blocks
        const int second = (blockIdx.x == 225);
        const float* W = second ? slW1b : slW1a;
        const int n = threadIdx.x;

        if (n < 128) {                    // fp16-pair W2 conversion
            const float* w2 = second ? cnW2 : slW2;
            unsigned int* dst = second ? w2hC : w2hS;
            h2 p; p.x = (_Float16)w2[2 * n]; p.y = (_Float16)w2[2 * n + 1];
            dst[n] = h2_bits(p);
        }

        float s0 = 0.f, s1 = 0.f, s2 = 0.f, s3 = 0.f;
#pragma unroll 4
        for (int k = 0; k < 256; k += 4) {
            s0 = fmaf(ftb2[k],     W[(k)     * 256 + n], s0);
            s1 = fmaf(ftb2[k + 1], W[(k + 1) * 256 + n], s1);
            s2 = fmaf(ftb2[k + 2], W[(k + 2) * 256 + n], s2);
            s3 = fmaf(ftb2[k + 3], W[(k + 3) * 256 + n], s3);
        }
        float s = (s0 + s1) + (s2 + s3);
        if (second) bB[n] = s + slb1[n];
        else        bA[n] = s;
        return;
    }

    int t = blockIdx.x * 256 + threadIdx.x;
    if (t < 49152) {                      // transpose paths
        const float* src; int K; unsigned short* dst;
        if (t < 16384) { src = ftW1; K = 512; dst = wt; }
        else {
            int m  = (t - 16384) >> 13;
            t = (t - 16384) & 8191; K = 256;
            switch (m) {
                case 0:  src = slW1a; dst = wt + 131072; break;
                case 1:  src = slW1b; dst = wt + 196608; break;
                case 2:  src = cnW1a; dst = wt + 262144; break;
                default: src = cnW1b; dst = wt + 327680; break;
            }
        }
        const int n  = t & 255;
        const int k0 = (t >> 8) * 8;
        unsigned int p[4];
#pragma unroll
        for (int j = 0; j < 4; ++j) {
            float f0 = src[(size_t)(k0 + 2 * j)     * 256 + n];
            float f1 = src[(size_t)(k0 + 2 * j + 1) * 256 + n];
            p[j] = pack2bf(f0, f1);
        }
        *(uint4*)(dst + (size_t)n * K + k0) = make_uint4(p[0], p[1], p[2], p[3]);
    } else {                              // ftW2 row-major bf16 copy
        const int lt = t - 49152;         // 0..8191
        const int k  = lt >> 5;
        const int n0 = (lt & 31) * 8;
        const float* src = ftW2 + (size_t)k * 256 + n0;
        float4 f0 = *(const float4*)(src);
        float4 f1 = *(const float4*)(src + 4);
        unsigned short* dst = wt + 393216 + (size_t)k * 256 + n0;
        *(uint4*)dst = make_uint4(pack2bf(f0.x, f0.y), pack2bf(f0.z, f0.w),
                                  pack2bf(f1.x, f1.y), pack2bf(f1.z, f1.w));
    }
}

// ---------------------------------------------------------------------------
// bf16 MFMA GEMM, two independent jobs in one dispatch (blockIdx.y-split).
// 64x64 tile, BK=32, 256 thr (4 waves). Single-barrier double-buffered LDS
// with register prefetch issued before the barrier (loads span barrier +
// compute). outMode: 0=f32, 1=bf16, 2=f16.
// NOTE (R4 lesson): keep phases as separate dispatches — a device-scope
// software barrier costs ~40us on gfx950 (XCD L2 flush), vs ~2us dispatch.
// ---------------------------------------------------------------------------
struct GJob {
    const void* A0; const void* A1; int aSplitBlk; int aBf16;
    const unsigned short* Wt0; const unsigned short* Wt1;
    const float* bias0; const float* bias1;
    int wRowSplitBlk; int wColSplitBlk;
    void* out; int outMode; int ldOut; int K; int relu;
};

__global__ __launch_bounds__(256) void gemm_mfma(GJob j0, GJob j1, int j0By)
{
    __shared__ unsigned short As[2][64][40];   // [buf][row][k], pad 32->40
    __shared__ unsigned short Bs[2][64][40];   // [buf][col][k] from W^T

    const bool firstJob = ((int)blockIdx.y < j0By);
    const GJob j = firstJob ? j0 : j1;
    const int by = firstJob ? blockIdx.y : blockIdx.y - j0By;
    const int bx = blockIdx.x;
    const int tid = threadIdx.x;
    const int K = j.K;

    const void* Abase; int arow0;
    if (by < j.aSplitBlk) { Abase = j.A0; arow0 = by * 64; }
    else                  { Abase = j.A1; arow0 = (by - j.aSplitBlk) * 64; }

    int wcolBlk = bx;
    bool second;
    if (j.wColSplitBlk > 0) {
        second = (bx >= j.wColSplitBlk);
        if (second) wcolBlk = bx - j.wColSplitBlk;
    } else {
        second = (by >= j.wRowSplitBlk);
    }
    const unsigned short* Wt = second ? j.Wt1 : j.Wt0;
    const float* bias        = second ? j.bias1 : j.bias0;
    const int wcol = wcolBlk * 64;

    const int r    = tid >> 2;          // 0..63 staging row (A) / col (B)
    const int kq   = (tid & 3) * 8;     // k offset within BK
    const int lane = tid & 63;
    const int wv   = tid >> 6;          // wave id 0..3
    const int col  = lane & 15;
    const int quad = lane >> 4;

    floatx4 acc[4] = {};

    uint4 apack, bpack;
    float4 af0, af1;
    const unsigned short* Abf = (const unsigned short*)Abase + (size_t)(arow0 + r) * K + kq;
    const float*          Afp = (const float*)Abase + (size_t)(arow0 + r) * K + kq;
    const unsigned short* Wp  = Wt + (size_t)(wcol + r) * K + kq;

    if (j.aBf16) apack = *(const uint4*)(Abf);
    else { af0 = *(const float4*)(Afp); af1 = *(const float4*)(Afp + 4); }
    bpack = *(const uint4*)(Wp);

    int p = 0;
    for (int k0 = 0; k0 < K; k0 += 32) {
        uint4 aw;
        if (j.aBf16) aw = apack;
        else aw = make_uint4(pack2bf(af0.x, af0.y), pack2bf(af0.z, af0.w),
                             pack2bf(af1.x, af1.y), pack2bf(af1.z, af1.w));
        uint4 bw = bpack;

        *(uint4*)&As[p][r][kq] = aw;
        *(uint4*)&Bs[p][r][kq] = bw;

        if (k0 + 32 < K) {               // prefetch next step; in flight across barrier
            if (j.aBf16) apack = *(const uint4*)(Abf + k0 + 32);
            else {
                af0 = *(const float4*)(Afp + k0 + 32);
                af1 = *(const float4*)(Afp + k0 + 32 + 4);
            }
            bpack = *(const uint4*)(Wp + k0 + 32);
        }

        __syncthreads();

        short8 bfrag = *(const short8*)&Bs[p][wv * 16 + col][quad * 8];
#pragma unroll
        for (int tm = 0; tm < 4; ++tm) {
            short8 afrag = *(const short8*)&As[p][tm * 16 + col][quad * 8];
            acc[tm] = __builtin_amdgcn_mfma_f32_16x16x32_bf16(afrag, bfrag, acc[tm], 0, 0, 0);
        }
        p ^= 1;
    }

    // D layout: col = lane&15, row = quad*4 + reg  [m89]
    const int ocol = bx * 64 + wv * 16 + col;
    const int bcol = wcol + wv * 16 + col;
    const float bv = bias ? bias[bcol] : 0.f;
#pragma unroll
    for (int tm = 0; tm < 4; ++tm) {
#pragma unroll
        for (int rr = 0; rr < 4; ++rr) {
            float v = acc[tm][rr] + bv;
            if (j.relu) v = fmaxf(v, 0.f);
            const size_t o = (size_t)(by * 64 + tm * 16 + quad * 4 + rr) * j.ldOut + ocol;
            if (j.outMode == 0)      ((float*)j.out)[o] = v;
            else if (j.outMode == 1) ((unsigned short*)j.out)[o] = (unsigned short)f2bf_bits(v);
            else                     ((_Float16*)j.out)[o] = (_Float16)v;
        }
    }
}

// ---------------------------------------------------------------------------
// Pair-score: out[b,i,j] = sigmoid( sum_h relu(a[b,i,h]+c[b,j,h])*W2[h] + b2 )
// a, c are f16 with row strides ldA/ldC. Block tile 64x32 (grid 8x4x8 = 256
// blocks = 1/CU), per-thread 4x2. Pipe balance: LDS 768 b128 x 12cyc = 9216
// cyc/CU; VALU with v_dot2_f32_f16 (pk_add+pk_max+dot2 per 2h per cell) =
// 3072 x 2cyc = 6144 cyc -> cleanly LDS-bound (~3.9us). W2h = fp16 pairs
// (prepped); fp32 W2 retained for the no-dot2 fallback path.
// Swizzle: 16B chunk ch of row r lives at ch ^ ((r>>1)&7):
//   a-reads (rows 4ti+rr) hit 4 distinct slots, c-reads (rows 2tj+e) 2-way.
// ---------------------------------------------------------------------------
__global__ __launch_bounds__(256) void pair_score(
    const unsigned short* __restrict__ Abase, int ldA,
    const unsigned short* __restrict__ Cbase, int ldC,
    const float* __restrict__ W2, const unsigned int* __restrict__ W2h,
    const float* __restrict__ b2p, float* __restrict__ out)
{
    __shared__ unsigned short aS[64][256];   // 32 KB
    __shared__ unsigned short cS[32][256];   // 16 KB

    const int tid = threadIdx.x;
    const int b   = blockIdx.z;
    const int i0b = blockIdx.y * 64;
    const int j0b = blockIdx.x * 32;

    {
        const int rr = tid >> 3;         // 0..31
        const int c8 = tid & 7;
        // a: 64 rows x 32 chunks (8 lanes x 16B = 128B coalesced per row seg)
#pragma unroll
        for (int rep = 0; rep < 8; ++rep) {
            const int li = rr + 32 * (rep & 1);
            const int ch = c8 + 8 * (rep >> 1);
            uint4 v = *(const uint4*)(Abase + ((size_t)b * N_ + i0b + li) * ldA + ch * 8);
            *(uint4*)&aS[li][(ch ^ ((li >> 1) & 7)) * 8] = v;
        }
        // c: 32 rows x 32 chunks
#pragma unroll
        for (int rep = 0; rep < 4; ++rep) {
            const int ch = c8 + 8 * rep;
            uint4 v = *(const uint4*)(Cbase + ((size_t)b * N_ + j0b + rr) * ldC + ch * 8);
            *(uint4*)&cS[rr][(ch ^ ((rr >> 1) & 7)) * 8] = v;
        }
    }
    __syncthreads();

    const int ti = tid >> 4, tj = tid & 15;
    const int ia = ti * 4, jc = tj * 2;
    const int k01 = (2 * ti) & 7;        // key for rows ia, ia+1
    const int k23 = (2 * ti + 1) & 7;    // key for rows ia+2, ia+3
    const int kc  = tj & 7;              // key for rows jc, jc+1

    float s[4][2] = {};

#pragma unroll 4
    for (int ch = 0; ch < 32; ++ch) {
        const uint4 a0 = *(const uint4*)&aS[ia    ][(ch ^ k01) * 8];
        const uint4 a1 = *(const uint4*)&aS[ia + 1][(ch ^ k01) * 8];
        const uint4 a2 = *(const uint4*)&aS[ia + 2][(ch ^ k23) * 8];
        const uint4 a3 = *(const uint4*)&aS[ia + 3][(ch ^ k23) * 8];
        const uint4 c0 = *(const uint4*)&cS[jc    ][(ch ^ kc) * 8];
        const uint4 c1 = *(const uint4*)&cS[jc + 1][(ch ^ kc) * 8];
#if __has_builtin(__builtin_amdgcn_fdot2)
        const uint4 wp = *(const uint4*)&W2h[ch * 4];   // wave-uniform s_load
#pragma unroll
        for (int u = 0; u < 4; ++u) {
            const h2 wv2 = as_h2(((const unsigned int*)&wp)[u]);
            const h2 hc0 = as_h2(((const unsigned int*)&c0)[u]);
            const h2 hc1 = as_h2(((const unsigned int*)&c1)[u]);
#define ACC2(su, ha, hc) { h2 t_ = relu2((ha) + (hc)); \
    su = __builtin_amdgcn_fdot2(t_, wv2, su, false); }
            {
                const h2 ha = as_h2(((const unsigned int*)&a0)[u]);
                ACC2(s[0][0], ha, hc0); ACC2(s[0][1], ha, hc1);
            }
            {
                const h2 ha = as_h2(((const unsigned int*)&a1)[u]);
                ACC2(s[1][0], ha, hc0); ACC2(s[1][1], ha, hc1);
            }
            {
                const h2 ha = as_h2(((const unsigned int*)&a2)[u]);
                ACC2(s[2][0], ha, hc0); ACC2(s[2][1], ha, hc1);
            }
            {
                const h2 ha = as_h2(((const unsigned int*)&a3)[u]);
                ACC2(s[3][0], ha, hc0); ACC2(s[3][1], ha, hc1);
            }
#undef ACC2
        }
#else
        const float* w = &W2[ch * 8];    // wave-uniform -> s_load
#pragma unroll
        for (int u = 0; u < 4; ++u) {
            const float w0 = w[2 * u], w1 = w[2 * u + 1];
            const h2 hc0 = as_h2(((const unsigned int*)&c0)[u]);
            const h2 hc1 = as_h2(((const unsigned int*)&c1)[u]);
#define ACC2(su, ha, hc) { h2 t_ = relu2((ha) + (hc)); \
    su = fmaf((float)t_.x, w0, su); su = fmaf((float)t_.y, w1, su); }
            {
                const h2 ha = as_h2(((const unsigned int*)&a0)[u]);
                ACC2(s[0][0], ha, hc0); ACC2(s[0][1], ha, hc1);
            }
            {
                const h2 ha = as_h2(((const unsigned int*)&a1)[u]);
                ACC2(s[1][0], ha, hc0); ACC2(s[1][1], ha, hc1);
            }
            {
                const h2 ha = as_h2(((const unsigned int*)&a2)[u]);
                ACC2(s[2][0], ha, hc0); ACC2(s[2][1], ha, hc1);
            }
            {
                const h2 ha = as_h2(((const unsigned int*)&a3)[u]);
                ACC2(s[3][0], ha, hc0); ACC2(s[3][1], ha, hc1);
            }
#undef ACC2
        }
#endif
    }

    const float bb = b2p[0];
#pragma unroll
    for (int rr = 0; rr < 4; ++rr) {
        float2 o;
        o.x = fast_sigmoid(s[rr][0] + bb);
        o.y = fast_sigmoid(s[rr][1] + bb);
        *(float2*)&out[((size_t)b * N_ + i0b + ia + rr) * N_ + j0b + jc] = o;
    }
}

// ---------------------------------------------------------------------------
// Invariance with folded finalize: last block (device-scope atomic counter)
// computes the scalar. accum[0]=stab, accum[1]=sd, accum[2]=block counter
// (accum zeroed by prep_weights block 0 earlier in the stream).
// ---------------------------------------------------------------------------
__global__ __launch_bounds__(256) void invariance_partial(
    const float* __restrict__ causal, float* __restrict__ accum,
    float* __restrict__ out_scalar)
{
    const int idx = blockIdx.x * 256 + threadIdx.x;  // 0..N*N-1
    float x[B_];
#pragma unroll
    for (int b = 0; b < B_; ++b) x[b] = causal[(size_t)b * (N_ * N_) + idx];

    float stab = 0.f, mean = 0.f;
#pragma unroll
    for (int b = 0; b < B_; ++b) {
        stab += fabsf(x[b] - x[(b + B_ - 1) % B_]);
        mean += x[b];
    }
    mean *= (1.f / B_);
    float var = 0.f;
#pragma unroll
    for (int b = 0; b < B_; ++b) {
        float d = x[b] - mean;
        var = fmaf(d, d, var);
    }
    float sd = sqrtf(var * (1.f / (B_ - 1)));

#pragma unroll
    for (int off = 32; off > 0; off >>= 1) {
        stab += __shfl_down(stab, off, 64);
        sd   += __shfl_down(sd, off, 64);
    }

    __shared__ float red[8];
    if ((threadIdx.x & 63) == 0) {
        red[threadIdx.x >> 6]       = stab;
        red[4 + (threadIdx.x >> 6)] = sd;
    }
    __syncthreads();
    if (threadIdx.x == 0) {
        float s = (red[0] + red[1]) + (red[2] + red[3]);
        float d = (red[4] + red[5]) + (red[6] + red[7]);
        atomicAdd(&accum[0], s);
        atomicAdd(&accum[1], d);
        __threadfence();
        unsigned int prev = atomicAdd((unsigned int*)&accum[2], 1u);
        if (prev == 255u) {              // last of 256 blocks
            float st  = atomicAdd(&accum[0], 0.f);   // device-scope read
            float sdt = atomicAdd(&accum[1], 0.f);
            float stability   = st  * (1.f / (float)(B_ * N_ * N_));
            float consistency = sdt * (1.f / (float)(N_ * N_));
            out_scalar[0] = 1.f - (stability + consistency) * 0.5f;
        }
    }
}

// ---------------------------------------------------------------------------
extern "C" void kernel_launch(void* const* d_in, const int* in_sizes, int n_in,
                              void* d_out, int out_size, void* d_ws, size_t ws_size,
                              hipStream_t stream)
{
    const float* img   = (const float*)d_in[0];
    const float* txt   = (const float*)d_in[1];
    const float* ftW1  = (const float*)d_in[2];
    const float* ftb1  = (const float*)d_in[3];
    const float* ftW2  = (const float*)d_in[4];
    const float* ftb2  = (const float*)d_in[5];
    const float* slW1a = (const float*)d_in[6];
    const float* slW1b = (const float*)d_in[7];
    const float* slb1  = (const float*)d_in[8];
    const float* slW2  = (const float*)d_in[9];
    const float* slb2  = (const float*)d_in[10];
    const float* cnW1a = (const float*)d_in[11];
    const float* cnW1b = (const float*)d_in[12];
    const float* cnb1  = (const float*)d_in[13];
    const float* cnW2  = (const float*)d_in[14];
    const float* cnb2  = (const float*)d_in[15];

    float* out       = (float*)d_out;
    float* structure = out;                              // [B,N,N] fp32
    float* causal    = out + (size_t)B_ * N_ * N_;       // [B,N,N] fp32
    float* inv       = out + 2 * (size_t)B_ * N_ * N_;   // scalar

    // workspace layout (ushort units from base):
    //   wt      0       .. 458752    prepped weights (incl ftW2row)
    //   wcombT  458752  .. 589824    [512][256] bf16 (a-half, b-half)
    //   bA @589824 (f32 x256), bB +256, accum +512 (4), w2hS +520 (128 u32),
    //   w2hC +648
    //   h1b     655360  .. 1703936   [4096][256] bf16
    //   acb     1703936 .. 2752512   [4096][256] f16  (a;c) / reused [2048][512] f16
    unsigned short* wt     = (unsigned short*)d_ws;
    unsigned short* wcombT = wt + 458752;
    float* bA    = (float*)(wt + 589824);
    float* bB    = bA + 256;
    float* accum = bA + 512;
    unsigned int* w2hS = (unsigned int*)(bA + 520);
    unsigned int* w2hC = w2hS + 128;
    unsigned short* h1b  = wt + 655360;
    unsigned short* acb  = wt + 1703936;
    unsigned short* ac2b = acb;                          // acb dead after P1

    dim3 blk(256);
    const int BIG = 1 << 20;

    const unsigned short* wtFT1 = wt;
    const unsigned short* wtSLA = wt + 131072;
    const unsigned short* wtSLB = wt + 196608;
    const unsigned short* wtCNA = wt + 262144;
    const unsigned short* wtCNB = wt + 327680;
    const unsigned short* ftW2r = wt + 393216;

    prep_weights<<<dim3(226), blk, 0, stream>>>(
        ftW1, ftW2, slW1a, slW1b, cnW1a, cnW1b, ftb2, slb1, slW2, cnW2,
        wt, bA, bB, accum, w2hS, w2hC);

    // Merged dispatch: job0 = G1 ([img;txt] @ ftW1 + b1, relu -> h1b bf16),
    // job1 = Wcomb^T = (ftW2 @ slW1x)^T via A=slW1x^T, B=ftW2 rows -> bf16.
    {
        GJob g1  = { img, txt, 32, 0, wtFT1, wtFT1, ftb1, ftb1, BIG, 0,
                     h1b, 1, 256, 512, 1 };
        GJob wcb = { wtSLA, wtSLB, 4, 1, ftW2r, ftW2r, nullptr, nullptr, BIG, 0,
                     wcombT, 1, 256, 256, 0 };
        gemm_mfma<<<dim3(4, 72), blk, 0, stream>>>(g1, wcb, 64);
    }

    // G2': h1 @ Wcomb + bias -> acb f16. rows 0..2047 (img): WcombA + bA;
    // rows 2048.. (txt): WcombB + bB.  (ftW2 folded via associativity)
    {
        GJob g2 = { h1b, h1b, BIG, 1, wcombT, wcombT + 65536, bA, bB, 32, 0,
                    acb, 2, 256, 256, 0 };
        gemm_mfma<<<dim3(4, 64), blk, 0, stream>>>(g2, g2, 64);
    }

    // P1: structure = pair(a, c), f16 inputs
    pair_score<<<dim3(8, 4, 8), blk, 0, stream>>>(
        acb, 256, acb + (size_t)2048 * 256, 256, slW2, w2hS, slb2, structure);

    // G4: structure @ [cnW1a | cnW1b(+cnb1)] -> ac2b f16 [2048][512]
    {
        GJob g4 = { structure, structure, BIG, 0, wtCNA, wtCNB, nullptr, cnb1, BIG, 4,
                    ac2b, 2, 512, 256, 0 };
        gemm_mfma<<<dim3(8, 32), blk, 0, stream>>>(g4, g4, 32);
    }

    // P2: causal = pair(a2, c2), f16 inputs
    pair_score<<<dim3(8, 4, 8), blk, 0, stream>>>(
        ac2b, 512, ac2b + 256, 512, cnW2, w2hC, cnb2, causal);

    // invariance (finalize folded into last block)
    invariance_partial<<<dim3(N_ * N_ / 256), blk, 0, stream>>>(causal, accum, inv);
}